// Round 5
// baseline (261.682 us; speedup 1.0000x reference)
//
#include <hip/hip_runtime.h>

using u16 = unsigned short;
using short4v = __attribute__((ext_vector_type(4))) short;
using short8 = __attribute__((ext_vector_type(8))) short;
using floatx4 = __attribute__((ext_vector_type(4))) float;

__device__ __forceinline__ float bf2f(u16 h) {
  union { unsigned int u; float f; } v;
  v.u = ((unsigned int)h) << 16;
  return v.f;
}
__device__ __forceinline__ u16 f2bf(float f) {
  union { float f; unsigned int u; } v;
  v.f = f;
  unsigned int u = v.u;
  return (u16)((u + 0x7FFFu + ((u >> 16) & 1u)) >> 16);
}
__device__ __forceinline__ u16 f2bf_rtz(float f) {  // truncate: 1 op
  union { float f; unsigned int u; } v;
  v.f = f;
  return (u16)(v.u >> 16);
}

// async global->LDS 16B copy (dest must be uniform base + lane*16)
typedef const __attribute__((address_space(1))) unsigned int* gas_t;
typedef __attribute__((address_space(3))) unsigned int* las_t;
__device__ __forceinline__ void gl_lds16(const u16* g, u16* l) {
  __builtin_amdgcn_global_load_lds((gas_t)(const void*)g, (las_t)(void*)l, 16,
                                   0, 0);
}

#define MFMA32 __builtin_amdgcn_mfma_f32_16x16x32_bf16
// 16x16x16 bf16 MFMA: prefer the native K=16 instruction; fall back to a
// zero-padded K=32 (adds 0*0 terms -> bit-identical result, always compiles).
__device__ __forceinline__ floatx4 mfma16(short4v a, short4v b, floatx4 c) {
#if __has_builtin(__builtin_amdgcn_mfma_f32_16x16x16bf16_1k)
  return __builtin_amdgcn_mfma_f32_16x16x16bf16_1k(a, b, c, 0, 0, 0);
#else
  short8 a8 = {a[0], a[1], a[2], a[3], 0, 0, 0, 0};
  short8 b8 = {b[0], b[1], b[2], b[3], 0, 0, 0, 0};
  return MFMA32(a8, b8, c, 0, 0, 0);
#endif
}

// Q prescale: 0.125 (hd^-0.5) * log2(e), so scores come out in log2 domain
#define QSCALE 0.180336880111f

// ---------------------------------------------------------------------------
// All f32 -> bf16 conversions in ONE launch.
// ---------------------------------------------------------------------------
__global__ __launch_bounds__(256) void cvt_all(
    const float* __restrict__ x, const float* __restrict__ wq,
    const float* __restrict__ wp, u16* __restrict__ xb, u16* __restrict__ wqb,
    u16* __restrict__ wpb) {
  int i = blockIdx.x * 256 + threadIdx.x;
  const float* src;
  u16* dst;
  int off;
  if (i < 1048576) {
    src = x; dst = xb; off = i;
  } else if (i < 1048576 + 786432) {
    src = wq; dst = wqb; off = i - 1048576;
  } else {
    src = wp; dst = wpb; off = i - 1835008;
  }
  float4 v = ((const float4*)src)[off];
  ushort4 o;
  o.x = f2bf(v.x);
  o.y = f2bf(v.y);
  o.z = f2bf(v.z);
  o.w = f2bf(v.w);
  ((ushort4*)dst)[off] = o;
}

// ---------------------------------------------------------------------------
// NT GEMM, m97 structure: C[M,N] = A[M,K] @ B[N,K]^T, bf16 in, fp32 acc.
// ---------------------------------------------------------------------------
template <int BIAS, int OUTBF16, int MT>
__global__ __launch_bounds__(256) void gemm_nt(
    const u16* __restrict__ A, const u16* __restrict__ B,
    const float* __restrict__ bias, void* __restrict__ Cout,
    int M, int N, int K) {
  constexpr int ROWS_A = MT * 32;
  __shared__ u16 As[ROWS_A * 32];
  __shared__ u16 Bs[128 * 32];
  const int tid = threadIdx.x;
  const int lane = tid & 63;
  const int wave = tid >> 6;
  const int col = lane & 15;
  const int quad = lane >> 4;
  const int bm = blockIdx.y * ROWS_A;
  const int bn = blockIdx.x * 128;
  const int wm = (wave >> 1) * (MT * 16);
  const int wn = (wave & 1) * 64;

  floatx4 acc[MT][4] = {};

  for (int kb = 0; kb < K; kb += 32) {
    __syncthreads();  // previous fragment reads done
#pragma unroll
    for (int c = tid; c < ROWS_A * 4; c += 256)
      gl_lds16(A + (size_t)(bm + (c >> 2)) * K + kb + (c & 3) * 8, As + c * 8);
#pragma unroll
    for (int c = tid; c < 512; c += 256)
      gl_lds16(B + (size_t)(bn + (c >> 2)) * K + kb + (c & 3) * 8, Bs + c * 8);
    __syncthreads();  // fills visible

    short8 af[MT], bfr[4];
#pragma unroll
    for (int i = 0; i < MT; i++)
      af[i] = *(const short8*)(As + (wm + i * 16 + col) * 32 + quad * 8);
#pragma unroll
    for (int i = 0; i < 4; i++)
      bfr[i] = *(const short8*)(Bs + (wn + i * 16 + col) * 32 + quad * 8);
#pragma unroll
    for (int mi = 0; mi < MT; mi++)
#pragma unroll
      for (int ni = 0; ni < 4; ni++)
        acc[mi][ni] = MFMA32(af[mi], bfr[ni], acc[mi][ni], 0, 0, 0);
  }

#pragma unroll
  for (int mi = 0; mi < MT; mi++) {
#pragma unroll
    for (int ni = 0; ni < 4; ni++) {
#pragma unroll
      for (int r = 0; r < 4; r++) {
        int row = bm + wm + mi * 16 + quad * 4 + r;
        int c = bn + wn + ni * 16 + col;
        float v = acc[mi][ni][r];
        if (BIAS) v += bias[c];
        if (OUTBF16)
          ((u16*)Cout)[(size_t)row * N + c] = f2bf(v);
        else
          ((float*)Cout)[(size_t)row * N + c] = v;
      }
    }
  }
}

// ---------------------------------------------------------------------------
// Fused RMSNorm+rotary (Q,K) + V transpose. Block = (bh, 64-token strip).
// ---------------------------------------------------------------------------
__global__ __launch_bounds__(256) void rope_v(
    const u16* __restrict__ qkv, const float* __restrict__ qw,
    const float* __restrict__ kw, const float* __restrict__ pcos,
    const float* __restrict__ psin, u16* __restrict__ Qb,
    u16* __restrict__ Kb, u16* __restrict__ Vt) {
  __shared__ u16 T[64 * 68];
  const int bh = blockIdx.x;       // b*16+h
  const int n0 = blockIdx.y * 64;  // token strip
  const int b = bh >> 4, h = bh & 15;
  const int tid = threadIdx.x;
  const int lane = tid & 63;
  const int wave = tid >> 6;

  const float qwl = qw[lane];
  const float kwl = kw[lane];
  for (int tt = 0; tt < 16; tt++) {
    const int n = n0 + wave * 16 + tt;
    const int t = b * 2048 + n;
    const u16* base = qkv + (size_t)t * 3072 + h * 64 + lane;
    float qv = bf2f(base[0]);
    float kv = bf2f(base[1024]);

    float sq = qv * qv, sk = kv * kv;
#pragma unroll
    for (int off = 32; off; off >>= 1) {
      sq += __shfl_xor(sq, off);
      sk += __shfl_xor(sk, off);
    }
    float qn = qv * rsqrtf(sq * (1.0f / 64.0f) + 1e-6f) * qwl;
    float kn = kv * rsqrtf(sk * (1.0f / 64.0f) + 1e-6f) * kwl;

    const int i = lane >> 1;
    const float c = pcos[n * 32 + i];
    const float s = psin[n * 32 + i];
    float qp = __shfl_xor(qn, 1);
    float kp = __shfl_xor(kn, 1);
    float qr, kr;
    if (lane & 1) {
      qr = qp * s + qn * c;
      kr = kp * s + kn * c;
    } else {
      qr = qn * c - qp * s;
      kr = kn * c - kp * s;
    }
    qr *= QSCALE;  // fold hd^-0.5 * log2(e) into Q

    const size_t o = ((size_t)bh * 2048 + n) * 64 + lane;
    Qb[o] = f2bf(qr);
    Kb[o] = f2bf(kr);
  }

  // ---- V transpose via LDS (coalesced both directions)
  const int q = tid & 7;
  const int r = tid >> 3;
#pragma unroll
  for (int rr = r; rr < 64; rr += 32) {
    short8 v = *(const short8*)(qkv + (size_t)(b * 2048 + n0 + rr) * 3072 +
                                2048 + h * 64 + q * 8);
    *(short8*)&T[rr * 68 + q * 8] = v;
  }
  __syncthreads();
#pragma unroll
  for (int dd = r; dd < 64; dd += 32) {
    short8 o;
#pragma unroll
    for (int j = 0; j < 8; j++) o[j] = T[(q * 8 + j) * 68 + dd];
    *(short8*)(Vt + (size_t)(bh * 64 + dd) * 2048 + n0 + q * 8) = o;
  }
}

// ---------------------------------------------------------------------------
// Flash attention v13 (causal). v12 post-mortem: LDS-BW-bound — each of 4
// q-split waves re-read the full 8KB K and V tiles (96KB LDS/block-step,
// matching the measured 1730cy step-slot). v13 splits waves by KEY: wave w
// owns keys w*16..w*16+15 of each tile, all 64 q of the strip.
//   * per-wave frags: K = 2 b128, V = 4 b64 (tile read ONCE per block total)
//     -> 32KB LDS/block-step (3x less).
//   * S^T = mfma32(K_w, Q^T): lane(col,quad) reg r = P[q=qg*16+col][key=
//     w*16+quad*4+r] — EXACTLY the 16x16x16 PV A-fragment: P stays in
//     registers (Pb LDS buffer deleted).
//   * PV + row-sum via mfma16 (native _1k builtin or zero-padded mfma32).
//   * accO is a per-wave key-partial -> all-to-all d-quarter reduction per
//     strip through the just-consumed K/V buffer (scratch, 4x4KB), with
//     compile-time indices only (rule #20: no runtime-indexed reg arrays).
//   * all LDS swizzles removed: measured counter invariance showed b128
//     wave reads are at the 8-dword/bank floor already; swizzle was a no-op.
// Keeps v12's uniform pairing (512 blocks x 33 steps; 2 blocks/CU, which is
// also the VGPR ceiling here), K+V dbuf gl_lds prefetch, one barrier/step,
// exp2-no-bias.
// ---------------------------------------------------------------------------
__global__ __launch_bounds__(256) void attn_flash(
    const u16* __restrict__ Q, const u16* __restrict__ Kk,
    const u16* __restrict__ Vt, u16* __restrict__ O) {
  __shared__ u16 Ks[2][2][64 * 32];  // [buf][d-half][key][32d]
  __shared__ u16 Vs[2][2][64 * 32];  // [buf][key-half][d][32keys]
  __shared__ float lsc[4][64];       // per-wave l partials
  const int id = blockIdx.x;         // 512 blocks
  const int bh = id & 31;
  const int pair = id >> 5;     // 0..15
  const int tileA = 31 - pair;  // 16..31
  const int tileB = pair;       // 0..15   (steps A+B == 33 always)
  const int tid = threadIdx.x;
  const int lane = tid & 63;
  const int wave = tid >> 6;
  const int col = lane & 15;
  const int quad = lane >> 4;
  const int srow = tid >> 2;      // staging: row 0..63
  const int spc = (tid & 3) * 8;  // staging: 16B piece

  const u16* Qh = Q + (size_t)bh * 2048 * 64;
  const u16* Kh = Kk + (size_t)bh * 2048 * 64;
  const u16* Vh = Vt + (size_t)bh * 64 * 2048;
  const int b = bh >> 4, h = bh & 15;

  const int q0A = tileA * 64;
  const int q0B = tileB * 64;
  const int nsA = tileA + 1;
  const int nsB = tileB + 1;

  short4v ones4;
#pragma unroll
  for (int j = 0; j < 4; j++) ones4[j] = (short)0x3F80;  // bf16 1.0

  floatx4 accO[4][4] = {};  // [qg][dg] partial O over this wave's keys
  floatx4 lacc[4] = {};     // [qg] partial row-sums, lacc[qg][r]=l(qg*16+quad*4+r)
  short8 aq[4][2];          // Q^T fragments for the current strip
  int cur = 0;

  auto load_aq = [&](int q0) {
#pragma unroll
    for (int qg = 0; qg < 4; qg++)
#pragma unroll
      for (int ks = 0; ks < 2; ks++)
        aq[qg][ks] = *(const short8*)(Qh + (size_t)(q0 + qg * 16 + col) * 64 +
                                      ks * 32 + quad * 8);
  };

  // one flash step over keys [j0,j0+64); prefetch [jnext,jnext+64) (-1: none)
  auto step = [&](int j0, int jnext, int q0) {
    if (jnext >= 0) {
#pragma unroll
      for (int half = 0; half < 2; half++) {
        gl_lds16(Kh + (size_t)(jnext + srow) * 64 + half * 32 + spc,
                 &Ks[cur ^ 1][half][0] + tid * 8);
        gl_lds16(Vh + (size_t)srow * 2048 + jnext + half * 32 + spc,
                 &Vs[cur ^ 1][half][0] + tid * 8);
      }
    }

    // this wave's K slice: A[row=key w*16+col][d-half ks]
    short8 ak[2];
#pragma unroll
    for (int ks = 0; ks < 2; ks++)
      ak[ks] = *(const short8*)&Ks[cur][ks][(wave * 16 + col) * 32 + quad * 8];
    // this wave's V slice: B[k=w*16+quad*4+j][d=dg*16+col], 4 consecutive keys
    short4v bv[4];
#pragma unroll
    for (int dg = 0; dg < 4; dg++)
      bv[dg] = *(const short4v*)&Vs[cur][wave >> 1]
                   [(dg * 16 + col) * 32 + (wave & 1) * 16 + quad * 4];

    // S^T: s[qg][r] = P-score[q=qg*16+col][key=j0+w*16+quad*4+r] (log2 dom)
    floatx4 s[4] = {};
#pragma unroll
    for (int qg = 0; qg < 4; qg++)
#pragma unroll
      for (int ks = 0; ks < 2; ks++)
        s[qg] = MFMA32(ak[ks], aq[qg][ks], s[qg], 0, 0, 0);

    // p = exp2(s); mask only on diagonal-adjacent tiles; pack -> PV A-frag
    short4v pa[4];
    if (j0 + 63 <= q0) {  // fully unmasked fast path
#pragma unroll
      for (int qg = 0; qg < 4; qg++)
#pragma unroll
        for (int r = 0; r < 4; r++)
          pa[qg][r] = (short)f2bf_rtz(exp2f(s[qg][r]));
    } else {
      const int keyg = j0 + wave * 16 + quad * 4;
#pragma unroll
      for (int qg = 0; qg < 4; qg++) {
        const int qq = q0 + qg * 16 + col;
#pragma unroll
        for (int r = 0; r < 4; r++) {
          float pv = (keyg + r <= qq) ? exp2f(s[qg][r]) : 0.0f;
          pa[qg][r] = (short)f2bf_rtz(pv);
        }
      }
    }

    // row-sum partials via MFMA against ones (D[q][*] identical per col)
#pragma unroll
    for (int qg = 0; qg < 4; qg++)
      lacc[qg] = mfma16(pa[qg], ones4, lacc[qg]);

    // PV: accO[qg][dg] += P[q][k_w] V[k_w][d]
#pragma unroll
    for (int dg = 0; dg < 4; dg++)
#pragma unroll
      for (int qg = 0; qg < 4; qg++)
        accO[qg][dg] = mfma16(pa[qg], bv[dg], accO[qg][dg]);

    __syncthreads();  // drains prefetch (vmcnt) + this step's LDS reads
    cur ^= 1;
  };

  // strip epilogue: all-to-all d-quarter reduction of accO + l totals + store
  auto finish = [&](int q0) {
    const int sbuf = cur ^ 1;  // buffer consumed by the last step = scratch
    float* const sc0 = (float*)&Ks[sbuf][0][0];  // 4 regions x 4KB
    float* const sc1 = (float*)&Ks[sbuf][1][0];  // ([64q][16d] f32 each,
    float* const sc2 = (float*)&Vs[sbuf][0][0];  //  q-granule XOR-spread)
    float* const sc3 = (float*)&Vs[sbuf][1][0];

    // publish l partials (value is col-invariant; col&3 picks qg statically)
    {
      floatx4 lv = lacc[0];
      lv = ((col & 3) == 1) ? lacc[1] : lv;
      lv = ((col & 3) == 2) ? lacc[2] : lv;
      lv = ((col & 3) == 3) ? lacc[3] : lv;
      *(floatx4*)&lsc[wave][(col & 3) * 16 + quad * 4] = lv;
    }

#pragma unroll
    for (int r = 1; r < 4; r++) {
#pragma unroll
      for (int w2 = 0; w2 < 4; w2++) {
        if (wave == w2) {  // wave-uniform branch; all indices compile-time
          const int dst = (w2 + r) & 3;
          float* d = dst == 0 ? sc0 : dst == 1 ? sc1 : dst == 2 ? sc2 : sc3;
#pragma unroll
          for (int qg = 0; qg < 4; qg++)
            *(floatx4*)&d[col * 64 + (((qg * 4 + quad) ^ col) & 15) * 4] =
                accO[qg][dst];
        }
      }
      __syncthreads();
#pragma unroll
      for (int w2 = 0; w2 < 4; w2++) {
        if (wave == w2) {
          const float* m = w2 == 0 ? sc0 : w2 == 1 ? sc1 : w2 == 2 ? sc2 : sc3;
#pragma unroll
          for (int qg = 0; qg < 4; qg++)
            accO[qg][w2] +=
                *(const floatx4*)&m[col * 64 +
                                    (((qg * 4 + quad) ^ col) & 15) * 4];
        }
      }
      __syncthreads();
    }

    // total l across waves (broadcast reads), normalize, store my d-quarter
#pragma unroll
    for (int qg = 0; qg < 4; qg++) {
      floatx4 lt = *(const floatx4*)&lsc[0][qg * 16 + quad * 4];
#pragma unroll
      for (int w2 = 1; w2 < 4; w2++)
        lt += *(const floatx4*)&lsc[w2][qg * 16 + quad * 4];
#pragma unroll
      for (int w2 = 0; w2 < 4; w2++) {
        if (wave == w2) {
#pragma unroll
          for (int r = 0; r < 4; r++) {
            const int qq = q0 + qg * 16 + quad * 4 + r;
            O[((size_t)(b * 2048 + qq) * 16 + h) * 64 + w2 * 16 + col] =
                f2bf(accO[qg][w2][r] / lt[r]);
          }
        }
      }
    }
    // reset accumulators for the next strip
#pragma unroll
    for (int qg = 0; qg < 4; qg++) {
#pragma unroll
      for (int dg = 0; dg < 4; dg++)
        accO[qg][dg] = (floatx4){0.f, 0.f, 0.f, 0.f};
      lacc[qg] = (floatx4){0.f, 0.f, 0.f, 0.f};
    }
  };

  // prologue: stage strip A tile 0 into buffer 0
  load_aq(q0A);
#pragma unroll
  for (int half = 0; half < 2; half++) {
    gl_lds16(Kh + (size_t)srow * 64 + half * 32 + spc,
             &Ks[0][half][0] + tid * 8);
    gl_lds16(Vh + (size_t)srow * 2048 + half * 32 + spc,
             &Vs[0][half][0] + tid * 8);
  }
  __syncthreads();

  // strip A; its last step prefetches strip B's tile 0 (j=0)
  for (int kt = 0; kt < nsA; kt++)
    step(kt * 64, (kt + 1 < nsA) ? (kt + 1) * 64 : 0, q0A);
  finish(q0A);

  load_aq(q0B);
  for (int kt = 0; kt < nsB; kt++)
    step(kt * 64, (kt + 1 < nsB) ? (kt + 1) * 64 : -1, q0B);
  finish(q0B);
}

// ---------------------------------------------------------------------------
extern "C" void kernel_launch(void* const* d_in, const int* in_sizes, int n_in,
                              void* d_out, int out_size, void* d_ws,
                              size_t ws_size, hipStream_t stream) {
  const float* x = (const float*)d_in[0];        // [2,2048,1024] f32
  const float* qkv_w = (const float*)d_in[1];    // [3072,1024] f32
  const float* q_norm_w = (const float*)d_in[2]; // [64] f32
  const float* k_norm_w = (const float*)d_in[3]; // [64] f32
  const float* proj_w = (const float*)d_in[4];   // [1024,1024] f32
  const float* proj_b = (const float*)d_in[5];   // [1024] f32
  const float* pos_cos = (const float*)d_in[6];  // [2048,32] f32
  const float* pos_sin = (const float*)d_in[7];  // [2048,32] f32
  // d_in[8] = causal mask: known analytically, ignored

  char* ws = (char*)d_ws;
  u16* xb = (u16*)ws;                          //  8 MB (4096*1024 bf16)
  u16* wqkvb = (u16*)(ws + 8388608);           //  6 MB (3072*1024 bf16)
  u16* wprojb = (u16*)(ws + 14680064);         //  2 MB (1024*1024 bf16)
  u16* qkv = (u16*)(ws + 16777216);            // 24 MB (4096*3072 bf16)
  u16* Qb = (u16*)(ws + 41943040);             //  8 MB
  u16* Kb = (u16*)(ws + 50331648);             //  8 MB
  u16* Vt = (u16*)(ws + 58720256);             //  8 MB
  u16* AO = (u16*)(ws + 67108864);             //  8 MB  (total 72 MB)

  // 0) all f32 -> bf16 conversions, one launch
  cvt_all<<<8192, 256, 0, stream>>>(x, qkv_w, proj_w, xb, wqkvb, wprojb);

  // 1) qkv = x @ qkv_w^T   (M=4096, N=3072, K=1024), 128x128 tiles, bf16 out
  gemm_nt<0, 1, 4><<<dim3(24, 32), 256, 0, stream>>>(xb, wqkvb, nullptr, qkv,
                                                     4096, 3072, 1024);

  // 2) fused rmsnorm+rope (Q,K) + V transpose
  rope_v<<<dim3(32, 32), 256, 0, stream>>>(qkv, q_norm_w, k_norm_w, pos_cos,
                                           pos_sin, Qb, Kb, Vt);

  // 3) causal flash attention v13: 512 paired blocks, key-split waves
  attn_flash<<<dim3(512), 256, 0, stream>>>(Qb, Kb, Vt, AO);

  // 4) out = AO @ proj_w^T + proj_b: 64x128 tiles -> 512 blocks (2/CU), f32
  gemm_nt<1, 0, 2><<<dim3(8, 64), 256, 0, stream>>>(AO, wprojb, proj_b,
                                                    (float*)d_out, 4096, 1024,
                                                    1024);
}

// Round 6
// 208.280 us; speedup vs baseline: 1.2564x; 1.2564x over previous
//
#include <hip/hip_runtime.h>

using u16 = unsigned short;
using short4v = __attribute__((ext_vector_type(4))) short;
using short8 = __attribute__((ext_vector_type(8))) short;
using floatx4 = __attribute__((ext_vector_type(4))) float;

__device__ __forceinline__ float bf2f(u16 h) {
  union { unsigned int u; float f; } v;
  v.u = ((unsigned int)h) << 16;
  return v.f;
}
__device__ __forceinline__ u16 f2bf(float f) {
  union { float f; unsigned int u; } v;
  v.f = f;
  unsigned int u = v.u;
  return (u16)((u + 0x7FFFu + ((u >> 16) & 1u)) >> 16);
}
__device__ __forceinline__ u16 f2bf_rtz(float f) {  // truncate: 1 op
  union { float f; unsigned int u; } v;
  v.f = f;
  return (u16)(v.u >> 16);
}

// async global->LDS 16B copy (dest must be uniform base + lane*16)
typedef const __attribute__((address_space(1))) unsigned int* gas_t;
typedef __attribute__((address_space(3))) unsigned int* las_t;
__device__ __forceinline__ void gl_lds16(const u16* g, u16* l) {
  __builtin_amdgcn_global_load_lds((gas_t)(const void*)g, (las_t)(void*)l, 16,
                                   0, 0);
}

#define MFMA32 __builtin_amdgcn_mfma_f32_16x16x32_bf16

// Q prescale: 0.125 (hd^-0.5) * log2(e), so scores come out in log2 domain
#define QSCALE 0.180336880111f

// ---------------------------------------------------------------------------
// All f32 -> bf16 conversions in ONE launch.
// ---------------------------------------------------------------------------
__global__ __launch_bounds__(256) void cvt_all(
    const float* __restrict__ x, const float* __restrict__ wq,
    const float* __restrict__ wp, u16* __restrict__ xb, u16* __restrict__ wqb,
    u16* __restrict__ wpb) {
  int i = blockIdx.x * 256 + threadIdx.x;
  const float* src;
  u16* dst;
  int off;
  if (i < 1048576) {
    src = x; dst = xb; off = i;
  } else if (i < 1048576 + 786432) {
    src = wq; dst = wqb; off = i - 1048576;
  } else {
    src = wp; dst = wpb; off = i - 1835008;
  }
  float4 v = ((const float4*)src)[off];
  ushort4 o;
  o.x = f2bf(v.x);
  o.y = f2bf(v.y);
  o.z = f2bf(v.z);
  o.w = f2bf(v.w);
  ((ushort4*)dst)[off] = o;
}

// ---------------------------------------------------------------------------
// NT GEMM v14: C[M,N] = A[M,K] @ B[N,K]^T, bf16 in, fp32 acc.
// Change vs v9-v13 (BK=32): BK=64 halves the per-K-step vmcnt(0)+barrier
// drains (the m97-structure's known ~20% stall), K=1024 -> 16 steps not 32.
// LDS rows are now 128B, which naively concentrates the b128 fragment read
// of 16 cols onto 4 banks (2x the bank floor); fixed with the both-sides
// XOR swizzle (rule 21): gl_lds dest stays LINEAR, the GLOBAL source piece
// is pre-swizzled s = p ^ (row&7) (same 128B row touched -> coalescing
// intact), and fragment reads use piece (kk*4+quad) ^ (col&7). Row bases
// (wm/wn/i*16) are multiples of 16 so row&7 == col&7 (static per lane).
// LDS: MT=4 32KB (3 blocks/CU, grid-limited as before), MT=2 24KB (2/CU).
// ---------------------------------------------------------------------------
template <int BIAS, int OUTBF16, int MT>
__global__ __launch_bounds__(256) void gemm_nt(
    const u16* __restrict__ A, const u16* __restrict__ B,
    const float* __restrict__ bias, void* __restrict__ Cout,
    int M, int N, int K) {
  constexpr int ROWS_A = MT * 32;
  __shared__ u16 As[ROWS_A * 64];
  __shared__ u16 Bs[128 * 64];
  const int tid = threadIdx.x;
  const int lane = tid & 63;
  const int wave = tid >> 6;
  const int col = lane & 15;
  const int quad = lane >> 4;
  const int bm = blockIdx.y * ROWS_A;
  const int bn = blockIdx.x * 128;
  const int wm = (wave >> 1) * (MT * 16);
  const int wn = (wave & 1) * 64;
  const int rsw = col & 7;  // == row&7 for every fragment row we read

  floatx4 acc[MT][4] = {};

  for (int kb = 0; kb < K; kb += 64) {
    __syncthreads();  // previous fragment reads done
    // stage A/B tiles: chunk c -> row c>>3, LDS piece c&7; source piece
    // s = p ^ (row&7) (inverse swizzle; LDS dest linear per gl_lds rule)
#pragma unroll
    for (int c = tid; c < ROWS_A * 8; c += 256) {
      const int row = c >> 3, s = (c & 7) ^ (row & 7);
      gl_lds16(A + (size_t)(bm + row) * K + kb + s * 8, As + c * 8);
    }
#pragma unroll
    for (int c = tid; c < 1024; c += 256) {
      const int row = c >> 3, s = (c & 7) ^ (row & 7);
      gl_lds16(B + (size_t)(bn + row) * K + kb + s * 8, Bs + c * 8);
    }
    __syncthreads();  // fills visible

#pragma unroll
    for (int kk = 0; kk < 2; kk++) {
      short8 af[MT], bfr[4];
#pragma unroll
      for (int i = 0; i < MT; i++)
        af[i] = *(const short8*)(As + (wm + i * 16 + col) * 64 +
                                 ((kk * 4 + quad) ^ rsw) * 8);
#pragma unroll
      for (int i = 0; i < 4; i++)
        bfr[i] = *(const short8*)(Bs + (wn + i * 16 + col) * 64 +
                                  ((kk * 4 + quad) ^ rsw) * 8);
#pragma unroll
      for (int mi = 0; mi < MT; mi++)
#pragma unroll
        for (int ni = 0; ni < 4; ni++)
          acc[mi][ni] = MFMA32(af[mi], bfr[ni], acc[mi][ni], 0, 0, 0);
    }
  }

#pragma unroll
  for (int mi = 0; mi < MT; mi++) {
#pragma unroll
    for (int ni = 0; ni < 4; ni++) {
#pragma unroll
      for (int r = 0; r < 4; r++) {
        int row = bm + wm + mi * 16 + quad * 4 + r;
        int c = bn + wn + ni * 16 + col;
        float v = acc[mi][ni][r];
        if (BIAS) v += bias[c];
        if (OUTBF16)
          ((u16*)Cout)[(size_t)row * N + c] = f2bf(v);
        else
          ((float*)Cout)[(size_t)row * N + c] = v;
      }
    }
  }
}

// ---------------------------------------------------------------------------
// Fused RMSNorm+rotary (Q,K) + V transpose. Block = (bh, 64-token strip).
// ---------------------------------------------------------------------------
__global__ __launch_bounds__(256) void rope_v(
    const u16* __restrict__ qkv, const float* __restrict__ qw,
    const float* __restrict__ kw, const float* __restrict__ pcos,
    const float* __restrict__ psin, u16* __restrict__ Qb,
    u16* __restrict__ Kb, u16* __restrict__ Vt) {
  __shared__ u16 T[64 * 68];
  const int bh = blockIdx.x;       // b*16+h
  const int n0 = blockIdx.y * 64;  // token strip
  const int b = bh >> 4, h = bh & 15;
  const int tid = threadIdx.x;
  const int lane = tid & 63;
  const int wave = tid >> 6;

  const float qwl = qw[lane];
  const float kwl = kw[lane];
  for (int tt = 0; tt < 16; tt++) {
    const int n = n0 + wave * 16 + tt;
    const int t = b * 2048 + n;
    const u16* base = qkv + (size_t)t * 3072 + h * 64 + lane;
    float qv = bf2f(base[0]);
    float kv = bf2f(base[1024]);

    float sq = qv * qv, sk = kv * kv;
#pragma unroll
    for (int off = 32; off; off >>= 1) {
      sq += __shfl_xor(sq, off);
      sk += __shfl_xor(sk, off);
    }
    float qn = qv * rsqrtf(sq * (1.0f / 64.0f) + 1e-6f) * qwl;
    float kn = kv * rsqrtf(sk * (1.0f / 64.0f) + 1e-6f) * kwl;

    const int i = lane >> 1;
    const float c = pcos[n * 32 + i];
    const float s = psin[n * 32 + i];
    float qp = __shfl_xor(qn, 1);
    float kp = __shfl_xor(kn, 1);
    float qr, kr;
    if (lane & 1) {
      qr = qp * s + qn * c;
      kr = kp * s + kn * c;
    } else {
      qr = qn * c - qp * s;
      kr = kn * c - kp * s;
    }
    qr *= QSCALE;  // fold hd^-0.5 * log2(e) into Q

    const size_t o = ((size_t)bh * 2048 + n) * 64 + lane;
    Qb[o] = f2bf(qr);
    Kb[o] = f2bf(kr);
  }

  // ---- V transpose via LDS (coalesced both directions)
  const int q = tid & 7;
  const int r = tid >> 3;
#pragma unroll
  for (int rr = r; rr < 64; rr += 32) {
    short8 v = *(const short8*)(qkv + (size_t)(b * 2048 + n0 + rr) * 3072 +
                                2048 + h * 64 + q * 8);
    *(short8*)&T[rr * 68 + q * 8] = v;
  }
  __syncthreads();
#pragma unroll
  for (int dd = r; dd < 64; dd += 32) {
    short8 o;
#pragma unroll
    for (int j = 0; j < 8; j++) o[j] = T[(q * 8 + j) * 68 + dd];
    *(short8*)(Vt + (size_t)(bh * 64 + dd) * 2048 + n0 + q * 8) = o;
  }
}

// ---------------------------------------------------------------------------
// Flash attention (causal) — v11, verbatim: the measured-best variant
// (44.7µs, round 3). v13's key-split rewrite spilled accumulators to
// scratch (VGPR 96 alloc vs ~112 needed; WRITE_SIZE tripled) -> 98µs;
// reverted. v11 structure: 1024 blocks (bh, 64q-tile) x 4 q-split waves,
// K+V double-buffered in LDS via gl_lds prefetched one step ahead, ONE
// barrier per step, S^T=K.Q^T MFMA, exp2-no-bias softmax, packed
// wave-private P through LDS, MFMA row-sums against ones.
// ---------------------------------------------------------------------------
#define PSTR 68
__global__ __launch_bounds__(256) void attn_flash(
    const u16* __restrict__ Q, const u16* __restrict__ Kk,
    const u16* __restrict__ Vt, u16* __restrict__ O) {
  __shared__ u16 Ks[2][2][64 * 32];  // [buf][d-half][key][32d]
  __shared__ u16 Vs[2][2][64 * 32];  // [buf][key-half][d][32keys]
  __shared__ u16 Pb[4][16 * PSTR];   // per-wave P, [q][key]
  const int id = blockIdx.x;
  const int bh = id & 31;
  const int tile = 31 - (id >> 5);  // big tiles dispatch first
  const int tid = threadIdx.x;
  const int lane = tid & 63;
  const int wave = tid >> 6;
  const int col = lane & 15;
  const int quad = lane >> 4;
  const int srow = tid >> 2;                      // staging: row 0..63
  const int sswz = ((tid & 3) ^ (srow & 3)) * 8;  // swizzled source piece
  const int rq = (quad ^ (col & 3)) * 8;          // matching fragment piece

  const u16* Qh = Q + (size_t)bh * 2048 * 64;
  const u16* Kh = Kk + (size_t)bh * 2048 * 64;
  const u16* Vh = Vt + (size_t)bh * 64 * 2048;
  const int b = bh >> 4, h = bh & 15;

  const int q0 = tile * 64 + wave * 16;  // this wave's 16 q-rows

  short8 aq[2];
#pragma unroll
  for (int ks = 0; ks < 2; ks++)
    aq[ks] = *(const short8*)(Qh + (size_t)(q0 + col) * 64 + ks * 32 + quad * 8);

  short8 ones;
#pragma unroll
  for (int j = 0; j < 8; j++) ones[j] = (short)0x3F80;  // bf16 1.0

  floatx4 accO[4] = {};
  floatx4 lacc = {};  // row-sums via MFMA: lacc[r] = l(q0+quad*4+r)
  const int nsteps = tile + 1;

  // prologue: stage K,V tile 0 into buffer 0 (swizzled source pieces)
#pragma unroll
  for (int half = 0; half < 2; half++) {
    gl_lds16(Kh + (size_t)srow * 64 + half * 32 + sswz,
             &Ks[0][half][0] + tid * 8);
    gl_lds16(Vh + (size_t)srow * 2048 + half * 32 + sswz,
             &Vs[0][half][0] + tid * 8);
  }
  __syncthreads();

  int cur = 0;
  for (int kt = 0; kt < nsteps; kt++) {
    const int j0 = kt * 64;

    // prefetch next K,V tile into the other buffer — issued before all of
    // this step's compute; the end-of-step barrier drains it ~for free
    if (kt + 1 < nsteps) {
      const int j1 = j0 + 64;
#pragma unroll
      for (int half = 0; half < 2; half++) {
        gl_lds16(Kh + (size_t)(j1 + srow) * 64 + half * 32 + sswz,
                 &Ks[cur ^ 1][half][0] + tid * 8);
        gl_lds16(Vh + (size_t)srow * 2048 + j1 + half * 32 + sswz,
                 &Vs[cur ^ 1][half][0] + tid * 8);
      }
    }

    // S^T = K Q^T from the resident buffer:
    // s[nt][r] = S^T[key=j0+nt*16+quad*4+r][q=q0+col]
    floatx4 s[4] = {};
#pragma unroll
    for (int nt = 0; nt < 4; nt++) {
#pragma unroll
      for (int ks = 0; ks < 2; ks++) {
        short8 bk = *(const short8*)&Ks[cur][ks][(nt * 16 + col) * 32 + rq];
        s[nt] = MFMA32(bk, aq[ks], s[nt], 0, 0, 0);
      }
    }

    // p = exp2(s); mask only on diagonal step; packed b64 P write
    if (j0 + 63 <= q0) {  // fully unmasked fast path
#pragma unroll
      for (int nt = 0; nt < 4; nt++) {
        short4v pk;
#pragma unroll
        for (int r = 0; r < 4; r++)
          pk[r] = (short)f2bf_rtz(exp2f(s[nt][r]));
        *(short4v*)&Pb[wave][col * PSTR + nt * 16 + quad * 4] = pk;
      }
    } else {  // diagonal-adjacent: per-key causal mask
      const int qg = q0 + col;
#pragma unroll
      for (int nt = 0; nt < 4; nt++) {
        const int jgb = j0 + nt * 16 + quad * 4;
        short4v pk;
#pragma unroll
        for (int r = 0; r < 4; r++) {
          float pv = (jgb + r <= qg) ? exp2f(s[nt][r]) : 0.0f;
          pk[r] = (short)f2bf_rtz(pv);
        }
        *(short4v*)&Pb[wave][col * PSTR + nt * 16 + quad * 4] = pk;
      }
    }
    // no barrier: Pb[wave] is wave-private, lgkmcnt orders write->read

    short8 ap[2];
#pragma unroll
    for (int kf = 0; kf < 2; kf++)
      ap[kf] = *(const short8*)&Pb[wave][col * PSTR + kf * 32 + quad * 8];

    // row-sums via MFMA against ones (A-operand already loaded)
#pragma unroll
    for (int kf = 0; kf < 2; kf++)
      lacc = MFMA32(ap[kf], ones, lacc, 0, 0, 0);

#pragma unroll
    for (int nt = 0; nt < 4; nt++) {
#pragma unroll
      for (int kf = 0; kf < 2; kf++) {
        short8 bv = *(const short8*)&Vs[cur][kf][(nt * 16 + col) * 32 + rq];
        accO[nt] = MFMA32(ap[kf], bv, accO[nt], 0, 0, 0);
      }
    }

    __syncthreads();  // drains prefetch (vmcnt) + this step's LDS reads
    cur ^= 1;
  }

  float lrec[4];
#pragma unroll
  for (int r = 0; r < 4; r++) lrec[r] = 1.0f / lacc[r];

  // epilogue: O token-major [b][n][h][d] feeding the proj GEMM
#pragma unroll
  for (int nt = 0; nt < 4; nt++) {
#pragma unroll
    for (int r = 0; r < 4; r++) {
      int qg = q0 + quad * 4 + r;
      int d = nt * 16 + col;
      O[((size_t)(b * 2048 + qg) * 16 + h) * 64 + d] =
          f2bf(accO[nt][r] * lrec[r]);
    }
  }
}

// ---------------------------------------------------------------------------
extern "C" void kernel_launch(void* const* d_in, const int* in_sizes, int n_in,
                              void* d_out, int out_size, void* d_ws,
                              size_t ws_size, hipStream_t stream) {
  const float* x = (const float*)d_in[0];        // [2,2048,1024] f32
  const float* qkv_w = (const float*)d_in[1];    // [3072,1024] f32
  const float* q_norm_w = (const float*)d_in[2]; // [64] f32
  const float* k_norm_w = (const float*)d_in[3]; // [64] f32
  const float* proj_w = (const float*)d_in[4];   // [1024,1024] f32
  const float* proj_b = (const float*)d_in[5];   // [1024] f32
  const float* pos_cos = (const float*)d_in[6];  // [2048,32] f32
  const float* pos_sin = (const float*)d_in[7];  // [2048,32] f32
  // d_in[8] = causal mask: known analytically, ignored

  char* ws = (char*)d_ws;
  u16* xb = (u16*)ws;                          //  8 MB (4096*1024 bf16)
  u16* wqkvb = (u16*)(ws + 8388608);           //  6 MB (3072*1024 bf16)
  u16* wprojb = (u16*)(ws + 14680064);         //  2 MB (1024*1024 bf16)
  u16* qkv = (u16*)(ws + 16777216);            // 24 MB (4096*3072 bf16)
  u16* Qb = (u16*)(ws + 41943040);             //  8 MB
  u16* Kb = (u16*)(ws + 50331648);             //  8 MB
  u16* Vt = (u16*)(ws + 58720256);             //  8 MB
  u16* AO = (u16*)(ws + 67108864);             //  8 MB  (total 72 MB)

  // 0) all f32 -> bf16 conversions, one launch
  cvt_all<<<8192, 256, 0, stream>>>(x, qkv_w, proj_w, xb, wqkvb, wprojb);

  // 1) qkv = x @ qkv_w^T   (M=4096, N=3072, K=1024), 128x128 tiles, bf16 out
  gemm_nt<0, 1, 4><<<dim3(24, 32), 256, 0, stream>>>(xb, wqkvb, nullptr, qkv,
                                                     4096, 3072, 1024);

  // 2) fused rmsnorm+rope (Q,K) + V transpose
  rope_v<<<dim3(32, 32), 256, 0, stream>>>(qkv, q_norm_w, k_norm_w, pos_cos,
                                           pos_sin, Qb, Kb, Vt);

  // 3) causal flash attention v11 (reverted best): 1024 blocks, 4 waves
  attn_flash<<<dim3(1024), 256, 0, stream>>>(Qb, Kb, Vt, AO);

  // 4) out = AO @ proj_w^T + proj_b: 64x128 tiles -> 512 blocks (2/CU), f32
  gemm_nt<1, 0, 2><<<dim3(8, 64), 256, 0, stream>>>(AO, wprojb, proj_b,
                                                    (float*)d_out, 4096, 1024,
                                                    1024);
}

// Round 7
// 201.647 us; speedup vs baseline: 1.2977x; 1.0329x over previous
//
#include <hip/hip_runtime.h>

using u16 = unsigned short;
using short4v = __attribute__((ext_vector_type(4))) short;
using short8 = __attribute__((ext_vector_type(8))) short;
using floatx4 = __attribute__((ext_vector_type(4))) float;

__device__ __forceinline__ float bf2f(u16 h) {
  union { unsigned int u; float f; } v;
  v.u = ((unsigned int)h) << 16;
  return v.f;
}
__device__ __forceinline__ u16 f2bf(float f) {
  union { float f; unsigned int u; } v;
  v.f = f;
  unsigned int u = v.u;
  return (u16)((u + 0x7FFFu + ((u >> 16) & 1u)) >> 16);
}
__device__ __forceinline__ u16 f2bf_rtz(float f) {  // truncate: 1 op
  union { float f; unsigned int u; } v;
  v.f = f;
  return (u16)(v.u >> 16);
}

// raw v_exp_f32 / v_rcp_f32 (exp2f() lowers to the safe OCML sequence with
// range/denormal fixup ~8-12 VALU ops; our |s|<=11.5 never needs it)
__device__ __forceinline__ float exp2_raw(float x) {
  return __builtin_amdgcn_exp2f(x);
}
__device__ __forceinline__ float rcp_raw(float x) {
  return __builtin_amdgcn_rcpf(x);
}

// async global->LDS 16B copy (dest must be uniform base + lane*16)
typedef const __attribute__((address_space(1))) unsigned int* gas_t;
typedef __attribute__((address_space(3))) unsigned int* las_t;
__device__ __forceinline__ void gl_lds16(const u16* g, u16* l) {
  __builtin_amdgcn_global_load_lds((gas_t)(const void*)g, (las_t)(void*)l, 16,
                                   0, 0);
}

#define MFMA32 __builtin_amdgcn_mfma_f32_16x16x32_bf16

// Q prescale: 0.125 (hd^-0.5) * log2(e), so scores come out in log2 domain
#define QSCALE 0.180336880111f

// ---------------------------------------------------------------------------
// All f32 -> bf16 conversions in ONE launch.
// ---------------------------------------------------------------------------
__global__ __launch_bounds__(256) void cvt_all(
    const float* __restrict__ x, const float* __restrict__ wq,
    const float* __restrict__ wp, u16* __restrict__ xb, u16* __restrict__ wqb,
    u16* __restrict__ wpb) {
  int i = blockIdx.x * 256 + threadIdx.x;
  const float* src;
  u16* dst;
  int off;
  if (i < 1048576) {
    src = x; dst = xb; off = i;
  } else if (i < 1048576 + 786432) {
    src = wq; dst = wqb; off = i - 1048576;
  } else {
    src = wp; dst = wpb; off = i - 1835008;
  }
  float4 v = ((const float4*)src)[off];
  ushort4 o;
  o.x = f2bf(v.x);
  o.y = f2bf(v.y);
  o.z = f2bf(v.z);
  o.w = f2bf(v.w);
  ((ushort4*)dst)[off] = o;
}

// ---------------------------------------------------------------------------
// NT GEMM v14 (kept): C[M,N] = A[M,K] @ B[N,K]^T, bf16 in, fp32 acc.
// BK=64 (halves barrier drains vs BK=32; measured ~-6µs total in r6) with
// both-sides XOR swizzle: gl_lds dest LINEAR, global source piece
// s = p ^ (row&7), fragment read piece (kk*4+quad) ^ (col&7).
// ---------------------------------------------------------------------------
template <int BIAS, int OUTBF16, int MT>
__global__ __launch_bounds__(256) void gemm_nt(
    const u16* __restrict__ A, const u16* __restrict__ B,
    const float* __restrict__ bias, void* __restrict__ Cout,
    int M, int N, int K) {
  constexpr int ROWS_A = MT * 32;
  __shared__ u16 As[ROWS_A * 64];
  __shared__ u16 Bs[128 * 64];
  const int tid = threadIdx.x;
  const int lane = tid & 63;
  const int wave = tid >> 6;
  const int col = lane & 15;
  const int quad = lane >> 4;
  const int bm = blockIdx.y * ROWS_A;
  const int bn = blockIdx.x * 128;
  const int wm = (wave >> 1) * (MT * 16);
  const int wn = (wave & 1) * 64;
  const int rsw = col & 7;  // == row&7 for every fragment row we read

  floatx4 acc[MT][4] = {};

  for (int kb = 0; kb < K; kb += 64) {
    __syncthreads();  // previous fragment reads done
#pragma unroll
    for (int c = tid; c < ROWS_A * 8; c += 256) {
      const int row = c >> 3, s = (c & 7) ^ (row & 7);
      gl_lds16(A + (size_t)(bm + row) * K + kb + s * 8, As + c * 8);
    }
#pragma unroll
    for (int c = tid; c < 1024; c += 256) {
      const int row = c >> 3, s = (c & 7) ^ (row & 7);
      gl_lds16(B + (size_t)(bn + row) * K + kb + s * 8, Bs + c * 8);
    }
    __syncthreads();  // fills visible

#pragma unroll
    for (int kk = 0; kk < 2; kk++) {
      short8 af[MT], bfr[4];
#pragma unroll
      for (int i = 0; i < MT; i++)
        af[i] = *(const short8*)(As + (wm + i * 16 + col) * 64 +
                                 ((kk * 4 + quad) ^ rsw) * 8);
#pragma unroll
      for (int i = 0; i < 4; i++)
        bfr[i] = *(const short8*)(Bs + (wn + i * 16 + col) * 64 +
                                  ((kk * 4 + quad) ^ rsw) * 8);
#pragma unroll
      for (int mi = 0; mi < MT; mi++)
#pragma unroll
        for (int ni = 0; ni < 4; ni++)
          acc[mi][ni] = MFMA32(af[mi], bfr[ni], acc[mi][ni], 0, 0, 0);
    }
  }

#pragma unroll
  for (int mi = 0; mi < MT; mi++) {
#pragma unroll
    for (int ni = 0; ni < 4; ni++) {
#pragma unroll
      for (int r = 0; r < 4; r++) {
        int row = bm + wm + mi * 16 + quad * 4 + r;
        int c = bn + wn + ni * 16 + col;
        float v = acc[mi][ni][r];
        if (BIAS) v += bias[c];
        if (OUTBF16)
          ((u16*)Cout)[(size_t)row * N + c] = f2bf(v);
        else
          ((float*)Cout)[(size_t)row * N + c] = v;
      }
    }
  }
}

// ---------------------------------------------------------------------------
// Fused RMSNorm+rotary (Q,K) + V transpose. Block = (bh, 64-token strip).
// ---------------------------------------------------------------------------
__global__ __launch_bounds__(256) void rope_v(
    const u16* __restrict__ qkv, const float* __restrict__ qw,
    const float* __restrict__ kw, const float* __restrict__ pcos,
    const float* __restrict__ psin, u16* __restrict__ Qb,
    u16* __restrict__ Kb, u16* __restrict__ Vt) {
  __shared__ u16 T[64 * 68];
  const int bh = blockIdx.x;       // b*16+h
  const int n0 = blockIdx.y * 64;  // token strip
  const int b = bh >> 4, h = bh & 15;
  const int tid = threadIdx.x;
  const int lane = tid & 63;
  const int wave = tid >> 6;

  const float qwl = qw[lane];
  const float kwl = kw[lane];
  for (int tt = 0; tt < 16; tt++) {
    const int n = n0 + wave * 16 + tt;
    const int t = b * 2048 + n;
    const u16* base = qkv + (size_t)t * 3072 + h * 64 + lane;
    float qv = bf2f(base[0]);
    float kv = bf2f(base[1024]);

    float sq = qv * qv, sk = kv * kv;
#pragma unroll
    for (int off = 32; off; off >>= 1) {
      sq += __shfl_xor(sq, off);
      sk += __shfl_xor(sk, off);
    }
    float qn = qv * rsqrtf(sq * (1.0f / 64.0f) + 1e-6f) * qwl;
    float kn = kv * rsqrtf(sk * (1.0f / 64.0f) + 1e-6f) * kwl;

    const int i = lane >> 1;
    const float c = pcos[n * 32 + i];
    const float s = psin[n * 32 + i];
    float qp = __shfl_xor(qn, 1);
    float kp = __shfl_xor(kn, 1);
    float qr, kr;
    if (lane & 1) {
      qr = qp * s + qn * c;
      kr = kp * s + kn * c;
    } else {
      qr = qn * c - qp * s;
      kr = kn * c - kp * s;
    }
    qr *= QSCALE;  // fold hd^-0.5 * log2(e) into Q

    const size_t o = ((size_t)bh * 2048 + n) * 64 + lane;
    Qb[o] = f2bf(qr);
    Kb[o] = f2bf(kr);
  }

  // ---- V transpose via LDS (coalesced both directions)
  const int q = tid & 7;
  const int r = tid >> 3;
#pragma unroll
  for (int rr = r; rr < 64; rr += 32) {
    short8 v = *(const short8*)(qkv + (size_t)(b * 2048 + n0 + rr) * 3072 +
                                2048 + h * 64 + q * 8);
    *(short8*)&T[rr * 68 + q * 8] = v;
  }
  __syncthreads();
#pragma unroll
  for (int dd = r; dd < 64; dd += 32) {
    short8 o;
#pragma unroll
    for (int j = 0; j < 8; j++) o[j] = T[(q * 8 + j) * 68 + dd];
    *(short8*)(Vt + (size_t)(bh * 64 + dd) * 2048 + n0 + q * 8) = o;
  }
}

// ---------------------------------------------------------------------------
// Flash attention v15 (causal) = v11 structure with ONE change: softmax
// exp2f() -> __builtin_amdgcn_exp2f (raw v_exp_f32). exp2f() lowers to the
// safe OCML sequence (~8-12 VALU ops/element with range+denormal fixup);
// at 16 elements/step/wave that VALU chain is the prime suspect for the
// 42% VALUBusy / 42% no-pipe-busy profile. |s| <= 11.5 -> v_exp_f32 exact
// enough (1 ULP) for bf16 P and the 0.03 absmax budget. Epilogue divide ->
// v_rcp_f32. Everything else byte-identical to the measured 45.3µs v11.
// ---------------------------------------------------------------------------
#define PSTR 68
__global__ __launch_bounds__(256) void attn_flash(
    const u16* __restrict__ Q, const u16* __restrict__ Kk,
    const u16* __restrict__ Vt, u16* __restrict__ O) {
  __shared__ u16 Ks[2][2][64 * 32];  // [buf][d-half][key][32d]
  __shared__ u16 Vs[2][2][64 * 32];  // [buf][key-half][d][32keys]
  __shared__ u16 Pb[4][16 * PSTR];   // per-wave P, [q][key]
  const int id = blockIdx.x;
  const int bh = id & 31;
  const int tile = 31 - (id >> 5);  // big tiles dispatch first
  const int tid = threadIdx.x;
  const int lane = tid & 63;
  const int wave = tid >> 6;
  const int col = lane & 15;
  const int quad = lane >> 4;
  const int srow = tid >> 2;                      // staging: row 0..63
  const int sswz = ((tid & 3) ^ (srow & 3)) * 8;  // swizzled source piece
  const int rq = (quad ^ (col & 3)) * 8;          // matching fragment piece

  const u16* Qh = Q + (size_t)bh * 2048 * 64;
  const u16* Kh = Kk + (size_t)bh * 2048 * 64;
  const u16* Vh = Vt + (size_t)bh * 64 * 2048;
  const int b = bh >> 4, h = bh & 15;

  const int q0 = tile * 64 + wave * 16;  // this wave's 16 q-rows

  short8 aq[2];
#pragma unroll
  for (int ks = 0; ks < 2; ks++)
    aq[ks] = *(const short8*)(Qh + (size_t)(q0 + col) * 64 + ks * 32 + quad * 8);

  short8 ones;
#pragma unroll
  for (int j = 0; j < 8; j++) ones[j] = (short)0x3F80;  // bf16 1.0

  floatx4 accO[4] = {};
  floatx4 lacc = {};  // row-sums via MFMA: lacc[r] = l(q0+quad*4+r)
  const int nsteps = tile + 1;

  // prologue: stage K,V tile 0 into buffer 0 (swizzled source pieces)
#pragma unroll
  for (int half = 0; half < 2; half++) {
    gl_lds16(Kh + (size_t)srow * 64 + half * 32 + sswz,
             &Ks[0][half][0] + tid * 8);
    gl_lds16(Vh + (size_t)srow * 2048 + half * 32 + sswz,
             &Vs[0][half][0] + tid * 8);
  }
  __syncthreads();

  int cur = 0;
  for (int kt = 0; kt < nsteps; kt++) {
    const int j0 = kt * 64;

    // prefetch next K,V tile into the other buffer — issued before all of
    // this step's compute; the end-of-step barrier drains it ~for free
    if (kt + 1 < nsteps) {
      const int j1 = j0 + 64;
#pragma unroll
      for (int half = 0; half < 2; half++) {
        gl_lds16(Kh + (size_t)(j1 + srow) * 64 + half * 32 + sswz,
                 &Ks[cur ^ 1][half][0] + tid * 8);
        gl_lds16(Vh + (size_t)srow * 2048 + j1 + half * 32 + sswz,
                 &Vs[cur ^ 1][half][0] + tid * 8);
      }
    }

    // S^T = K Q^T from the resident buffer:
    // s[nt][r] = S^T[key=j0+nt*16+quad*4+r][q=q0+col]
    floatx4 s[4] = {};
#pragma unroll
    for (int nt = 0; nt < 4; nt++) {
#pragma unroll
      for (int ks = 0; ks < 2; ks++) {
        short8 bk = *(const short8*)&Ks[cur][ks][(nt * 16 + col) * 32 + rq];
        s[nt] = MFMA32(bk, aq[ks], s[nt], 0, 0, 0);
      }
    }

    // p = exp2(s); mask only on diagonal step; packed b64 P write
    if (j0 + 63 <= q0) {  // fully unmasked fast path
#pragma unroll
      for (int nt = 0; nt < 4; nt++) {
        short4v pk;
#pragma unroll
        for (int r = 0; r < 4; r++)
          pk[r] = (short)f2bf_rtz(exp2_raw(s[nt][r]));
        *(short4v*)&Pb[wave][col * PSTR + nt * 16 + quad * 4] = pk;
      }
    } else {  // diagonal-adjacent: per-key causal mask
      const int qg = q0 + col;
#pragma unroll
      for (int nt = 0; nt < 4; nt++) {
        const int jgb = j0 + nt * 16 + quad * 4;
        short4v pk;
#pragma unroll
        for (int r = 0; r < 4; r++) {
          float pv = (jgb + r <= qg) ? exp2_raw(s[nt][r]) : 0.0f;
          pk[r] = (short)f2bf_rtz(pv);
        }
        *(short4v*)&Pb[wave][col * PSTR + nt * 16 + quad * 4] = pk;
      }
    }
    // no barrier: Pb[wave] is wave-private, lgkmcnt orders write->read

    short8 ap[2];
#pragma unroll
    for (int kf = 0; kf < 2; kf++)
      ap[kf] = *(const short8*)&Pb[wave][col * PSTR + kf * 32 + quad * 8];

    // row-sums via MFMA against ones (A-operand already loaded)
#pragma unroll
    for (int kf = 0; kf < 2; kf++)
      lacc = MFMA32(ap[kf], ones, lacc, 0, 0, 0);

#pragma unroll
    for (int nt = 0; nt < 4; nt++) {
#pragma unroll
      for (int kf = 0; kf < 2; kf++) {
        short8 bv = *(const short8*)&Vs[cur][kf][(nt * 16 + col) * 32 + rq];
        accO[nt] = MFMA32(ap[kf], bv, accO[nt], 0, 0, 0);
      }
    }

    __syncthreads();  // drains prefetch (vmcnt) + this step's LDS reads
    cur ^= 1;
  }

  float lrec[4];
#pragma unroll
  for (int r = 0; r < 4; r++) lrec[r] = rcp_raw(lacc[r]);

  // epilogue: O token-major [b][n][h][d] feeding the proj GEMM
#pragma unroll
  for (int nt = 0; nt < 4; nt++) {
#pragma unroll
    for (int r = 0; r < 4; r++) {
      int qg = q0 + quad * 4 + r;
      int d = nt * 16 + col;
      O[((size_t)(b * 2048 + qg) * 16 + h) * 64 + d] =
          f2bf(accO[nt][r] * lrec[r]);
    }
  }
}

// ---------------------------------------------------------------------------
extern "C" void kernel_launch(void* const* d_in, const int* in_sizes, int n_in,
                              void* d_out, int out_size, void* d_ws,
                              size_t ws_size, hipStream_t stream) {
  const float* x = (const float*)d_in[0];        // [2,2048,1024] f32
  const float* qkv_w = (const float*)d_in[1];    // [3072,1024] f32
  const float* q_norm_w = (const float*)d_in[2]; // [64] f32
  const float* k_norm_w = (const float*)d_in[3]; // [64] f32
  const float* proj_w = (const float*)d_in[4];   // [1024,1024] f32
  const float* proj_b = (const float*)d_in[5];   // [1024] f32
  const float* pos_cos = (const float*)d_in[6];  // [2048,32] f32
  const float* pos_sin = (const float*)d_in[7];  // [2048,32] f32
  // d_in[8] = causal mask: known analytically, ignored

  char* ws = (char*)d_ws;
  u16* xb = (u16*)ws;                          //  8 MB (4096*1024 bf16)
  u16* wqkvb = (u16*)(ws + 8388608);           //  6 MB (3072*1024 bf16)
  u16* wprojb = (u16*)(ws + 14680064);         //  2 MB (1024*1024 bf16)
  u16* qkv = (u16*)(ws + 16777216);            // 24 MB (4096*3072 bf16)
  u16* Qb = (u16*)(ws + 41943040);             //  8 MB
  u16* Kb = (u16*)(ws + 50331648);             //  8 MB
  u16* Vt = (u16*)(ws + 58720256);             //  8 MB
  u16* AO = (u16*)(ws + 67108864);             //  8 MB  (total 72 MB)

  // 0) all f32 -> bf16 conversions, one launch
  cvt_all<<<8192, 256, 0, stream>>>(x, qkv_w, proj_w, xb, wqkvb, wprojb);

  // 1) qkv = x @ qkv_w^T   (M=4096, N=3072, K=1024), 128x128 tiles, bf16 out
  gemm_nt<0, 1, 4><<<dim3(24, 32), 256, 0, stream>>>(xb, wqkvb, nullptr, qkv,
                                                     4096, 3072, 1024);

  // 2) fused rmsnorm+rope (Q,K) + V transpose
  rope_v<<<dim3(32, 32), 256, 0, stream>>>(qkv, q_norm_w, k_norm_w, pos_cos,
                                           pos_sin, Qb, Kb, Vt);

  // 3) causal flash attention v15: v11 + raw v_exp_f32 softmax
  attn_flash<<<dim3(1024), 256, 0, stream>>>(Qb, Kb, Vt, AO);

  // 4) out = AO @ proj_w^T + proj_b: 64x128 tiles -> 512 blocks (2/CU), f32
  gemm_nt<1, 0, 2><<<dim3(8, 64), 256, 0, stream>>>(AO, wprojb, proj_b,
                                                    (float*)d_out, 4096, 1024,
                                                    1024);
}